// Round 6
// baseline (314.034 us; speedup 1.0000x reference)
//
#include <hip/hip_runtime.h>
#include <cstdint>

// Problem constants (from reference)
#define BB 32
#define TV 8192
#define KK 64
#define TS 128
#define MARGIN_F 0.1f
#define LAMBDA_F 0.5f

typedef unsigned long long u64;
typedef unsigned int u32;

static constexpr int KB_PAIRS = KK * BB;       // 2048 (k,b) rows
static constexpr int W32_PER_B = TV / 32;      // 256 u32 mask words per batch
static constexpr int W64_PER_B = TV / 64;      // 128 u64 mask words per batch

// Workspace layout (u32 units from base):
//   gsa[2048] f32 | gsv[2048] f32 | gca[2048] f32 | len[32] i32 | mw[32] i32
//   vbit[32*256] u32 (32 KB) | pl[32*64*256] u32 (2 MB)
// pl u64-word g of (b,k) row = u32 pair {2g, 2g+1} (little-endian halves).
//
// R9: SPLIT the fusion. R8's verdict: tile rotation = +5% only; the monolith
// pins at ~1 TB/s demand (VALU 13%, MLP/CU ~2) across 4 structural variants.
// Common factor: fused waves alternate serial ballot chains, barriers, and
// strided bursts -> mostly not issuing; grid locked at residency (no
// backfill). R9 ablates by splitting into 3 streaming kernels, each with its
// own counter row: plane_kernel (gt ~96MB, 32 waves/CU, backfill),
// reduce_kernel (pi ~50MB, block per (k,b), direct stores, no atomics),
// fin. Prediction: total 83 -> 35-55us; whichever sub-kernel reads ~1 TB/s
// is the isolated culprit for the next round.

// ---------------------------------------------------------------------------
// K2: ballot-transpose gt -> packed planes. Block = one 64-row group of one
// batch (2 waves, each a 32-row half). blk = b*128 + g.
// ---------------------------------------------------------------------------
__global__ __launch_bounds__(128, 4) void plane_kernel(
    const int* __restrict__ idx, const int* __restrict__ gt,
    const int* __restrict__ mv, u32* __restrict__ vbit, u32* __restrict__ pl,
    int* __restrict__ len, int* __restrict__ mw) {
  const int lane = threadIdx.x & 63;
  const int h = threadIdx.x >> 6;              // half: rows [32h, 32h+32)
  const int blk = blockIdx.x;
  const int b = blk >> 7;                      // 0..31
  const int g = blk & 127;                     // 64-row group 0..127
  const int w32 = g * 2 + h;                   // 32-bit mask-word index
  const int grow = b * TV + g * 64 + h * 32;   // global first row

  // valid bits for these 32 rows (R5-verified half-ballot: lanes>=32 give 0)
  const int mvv = (lane < 32) ? mv[grow + lane] : 0;
  const u32 V = (u32)__ballot(mvv != 0);
  if (lane == 0) {
    vbit[b * W32_PER_B + w32] = V;
    if (V) {
      atomicAdd(&len[b], __popc(V));
      atomicMax(&mw[b], w32);
    }
  }

  u32 plane = 0;
  if (V) {                                     // wave-uniform (ballot result)
    const int c = idx[lane];                   // lane extracts column for k=lane
    const int csel = c & 3, csh = c >> 2;
    const int4* rowp = (const int4*)(gt + (size_t)grow * TS);
#pragma unroll
    for (int ch = 0; ch < 16; ++ch) {          // 1KB wave-load = 2 rows
      const int4 v = rowp[ch * 64 + lane];
      const u64 b0 = __ballot(v.x > 0);
      const u64 b1 = __ballot(v.y > 0);
      const u64 b2 = __ballot(v.z > 0);
      const u64 b3 = __ballot(v.w > 0);
      const u64 sel =
          (csel == 0) ? b0 : (csel == 1) ? b1 : (csel == 2) ? b2 : b3;
      plane |= (u32)((sel >> csh) & 1ull) << (2 * ch);         // row 2ch
      plane |= (u32)((sel >> (32 + csh)) & 1ull) << (2 * ch + 1); // row 2ch+1
    }
    plane &= V;                                // aligned requires valid
  }
  // ALWAYS store (ws poisoned; reduce popcounts the whole row)
  pl[((size_t)(b * KK + lane) * W64_PER_B + g) * 2 + h] = plane;
}

// ---------------------------------------------------------------------------
// K3: one block per (k,b) row of pi. Direct stores, no global atomics.
// ---------------------------------------------------------------------------
__global__ __launch_bounds__(256, 4) void reduce_kernel(
    const float* __restrict__ po, const float* __restrict__ pi,
    const u32* __restrict__ vbit, const u32* __restrict__ pl,
    const int* __restrict__ mw,
    float* __restrict__ gsa, float* __restrict__ gsv,
    float* __restrict__ gca) {
  const int tid = threadIdx.x;
  const int lane = tid & 63;
  const int w = tid >> 6;
  const int kb = blockIdx.x;                   // k*BB + b
  const int b = kb & (BB - 1);
  const int k = kb >> 5;
  const u64* plrow = (const u64*)pl + (size_t)(b * KK + k) * W64_PER_B;
  const u64* vrow = (const u64*)vbit + (size_t)b * W64_PER_B;
  const float* pirow = pi + (size_t)kb * TV;
  const float* porow = po + (size_t)b * TV;

  __shared__ float rs[4][2];
  __shared__ int rca;
  if (tid == 0) rca = 0;
  __syncthreads();

  // chunks of 1024 floats; clip by highest valid word (mw in u32-word units)
  const int nch = min(8, (mw[b] + 32) >> 5);
  const int sh = (tid & 15) * 4;               // nibble of this thread's 4 t's
  float sa = 0.f, sv = 0.f;
#pragma unroll 2
  for (int c = 0; c < nch; ++c) {
    const int t = c * 1024 + tid * 4;
    const int widx = t >> 6;                   // u64 word
    const u64 vw = vrow[widx];                 // 16 lanes share -> L1 broadcast
    const u32 vb4 = (u32)((vw >> sh) & 15ull);
    if (vb4) {                                 // aligned subset of valid
      const u64 aw = plrow[widx];
      const u32 ab4 = (u32)((aw >> sh) & 15ull);
      const float4 x = *(const float4*)(pirow + t);
      const float4 p = *(const float4*)(porow + t);   // po: L2-resident (1MB)
      const float e0 =
          fabsf(__fdividef(1.f, 1.f + __expf(-p.x)) -
                __fdividef(1.f, 1.f + __expf(-x.x)));
      const float e1 =
          fabsf(__fdividef(1.f, 1.f + __expf(-p.y)) -
                __fdividef(1.f, 1.f + __expf(-x.y)));
      const float e2 =
          fabsf(__fdividef(1.f, 1.f + __expf(-p.z)) -
                __fdividef(1.f, 1.f + __expf(-x.z)));
      const float e3 =
          fabsf(__fdividef(1.f, 1.f + __expf(-p.w)) -
                __fdividef(1.f, 1.f + __expf(-x.w)));
      if (vb4 & 1u) sv += e0;
      if (vb4 & 2u) sv += e1;
      if (vb4 & 4u) sv += e2;
      if (vb4 & 8u) sv += e3;
      if (ab4 & 1u) sa += e0;
      if (ab4 & 2u) sa += e1;
      if (ab4 & 4u) sa += e2;
      if (ab4 & 8u) sa += e3;
    }
  }
  // 64-lane butterfly, then 4-wave combine
#pragma unroll
  for (int off = 32; off; off >>= 1) {
    sa += __shfl_xor(sa, off);
    sv += __shfl_xor(sv, off);
  }
  if (lane == 0) {
    rs[w][0] = sa;
    rs[w][1] = sv;
  }
  if (tid < W64_PER_B) atomicAdd(&rca, __popcll(plrow[tid]));  // LDS atomic
  __syncthreads();
  if (tid == 0) {
    gsa[kb] = rs[0][0] + rs[1][0] + rs[2][0] + rs[3][0];
    gsv[kb] = rs[0][1] + rs[1][1] + rs[2][1] + rs[3][1];
    gca[kb] = (float)rca;
  }
}

// ---------------------------------------------------------------------------
// Finalize: 1 block over the 2048 (k,b) pairs (logic verified in R2/R3).
// ---------------------------------------------------------------------------
__global__ __launch_bounds__(256) void fin_kernel(
    const float* __restrict__ gsa, const float* __restrict__ gsv,
    const float* __restrict__ gca, const int* __restrict__ len,
    float* __restrict__ out) {
  float s = 0.f;
  for (int i = threadIdx.x; i < KB_PAIRS; i += 256) {
    const int b = i & (BB - 1);
    const float ca = gca[i];
    const float cn = (float)len[b] - ca;
    if (ca > 0.f && cn > 0.f) {
      const float sa = gsa[i];
      const float sv = gsv[i];
      const float d = MARGIN_F - (sa / ca - (sv - sa) / cn);
      s += d > 0.f ? d : 0.f;
    }
  }
#pragma unroll
  for (int off = 32; off > 0; off >>= 1) s += __shfl_down(s, off);
  __shared__ float ws4[4];
  if ((threadIdx.x & 63) == 0) ws4[threadIdx.x >> 6] = s;
  __syncthreads();
  if (threadIdx.x == 0) {
    const float S = ws4[0] + ws4[1] + ws4[2] + ws4[3];
    const float ac = S * (1.0f / (float)KB_PAIRS);
    out[0] = ac;
    out[1] = ac * LAMBDA_F;
  }
}

extern "C" void kernel_launch(void* const* d_in, const int* in_sizes, int n_in,
                              void* d_out, int out_size, void* d_ws, size_t ws_size,
                              hipStream_t stream) {
  const float* pred_orig = (const float*)d_in[0];   // [B,TV] fp32
  const float* pred_int  = (const float*)d_in[1];   // [K,B,TV] fp32
  const int*   idx       = (const int*)d_in[2];     // [K] int32
  const int*   gt        = (const int*)d_in[3];     // [B,TV,TS] int32
  const int*   mv        = (const int*)d_in[4];     // [B,TV] int32
  float* out = (float*)d_out;

  float* gsa = (float*)d_ws;                        // [2048]
  float* gsv = gsa + KB_PAIRS;                      // [2048]
  float* gca = gsv + KB_PAIRS;                      // [2048]
  int*   len = (int*)(gca + KB_PAIRS);              // [32]
  int*   mw  = len + BB;                            // [32]
  u32*   vbit = (u32*)(mw + BB);                    // [32*256]  32 KB
  u32*   pl   = vbit + BB * W32_PER_B;              // [32*64*256] 2 MB

  // only len+mw need zeroing (256 B); everything else is written before read
  hipMemsetAsync(len, 0, 2 * BB * sizeof(int), stream);
  plane_kernel<<<BB * (TV / 64), 128, 0, stream>>>(idx, gt, mv, vbit, pl, len,
                                                   mw);
  reduce_kernel<<<KB_PAIRS, 256, 0, stream>>>(pred_orig, pred_int, vbit, pl,
                                              mw, gsa, gsv, gca);
  fin_kernel<<<1, 256, 0, stream>>>(gsa, gsv, gca, len, out);
}

// Round 7
// 285.831 us; speedup vs baseline: 1.0987x; 1.0987x over previous
//
#include <hip/hip_runtime.h>
#include <cstdint>

// Problem constants (from reference)
#define BB 32
#define TV 8192
#define KK 64
#define TS 128
#define MARGIN_F 0.1f
#define LAMBDA_F 0.5f

typedef unsigned long long u64;
typedef unsigned int u32;

static constexpr int KB_PAIRS = KK * BB;       // 2048 (k,b) rows
static constexpr int W32_PER_B = TV / 32;      // 256 u32 mask words per batch
static constexpr int W64_PER_B = TV / 64;      // 128 u64 mask words per batch
static constexpr int ROWS = 128;               // t-rows per plane block

// Workspace layout (u32 units from base):
//   gsa[2048] f32 | gsv[2048] f32 | gca[2048] f32 | len[32] i32 | mw[32] i32
//   vbit[32*256] u32 (32 KB) | pl[32*64*256] u32 (2 MB)
//
// R10: R9's split isolated the cost: plane_kernel = 119us ALONE (vs 83us
// whole monolith) at VALU 3% / HBM 6% / occupancy 69% / VGPR 24 -> the
// load->ballot chain schedules to MLP=1 per wave (compiler sinks each int4
// load against its 4 dependent ballots; same pathology as R5/R6). Fix:
// TRANSPOSE VIA LDS. Stage gt tile with global_load_lds DMA (16B/lane,
// 16x1KB in flight per wave, NO consumers until barrier -> MLP by
// construction), then lane=k ds_reads its column idx[k] (banks random,
// ~4-way ~= 1.6x, m136) and builds the 32-bit plane in registers.
// reduce/fin/layouts byte-identical to R9 (reduce+fin ~= 20us, proven).
// Prediction: plane 119 -> 25-40us, VALU -> 10-15%, FETCH ~50MB unchanged;
// absmax!=0 => DMA addressing wrong -> reg-staging fallback; plane >80us
// with same FETCH => serialization wasn't the limiter -> probe TCC_HIT.

// ---------------------------------------------------------------------------
// K2 v2: LDS-transpose. Block = 128 rows of one batch; blk = b*64 + tile.
// ---------------------------------------------------------------------------
__global__ __launch_bounds__(256, 2) void plane_kernel(
    const int* __restrict__ idx, const int* __restrict__ gt,
    const int* __restrict__ mv, u32* __restrict__ vbit, u32* __restrict__ pl,
    int* __restrict__ len, int* __restrict__ mw) {
  const int tid = threadIdx.x;
  const int lane = tid & 63;
  const int w = tid >> 6;                      // 0..3
  const int blk = blockIdx.x;
  const int b = blk >> 6;                      // 0..31
  const int tile = blk & 63;                   // 128-row tile 0..63
  const int t0 = tile * ROWS;

  __shared__ u32 sV[4];
  __shared__ int gtile[ROWS * TS];             // 64 KB staged gt tile

  // validity ballot: wave w covers rows [t0+32w, t0+32w+32)
  const int rbase = b * TV + t0 + 32 * w;
  const int mvv = (lane < 32) ? mv[rbase + lane] : 0;
  const u32 V32 = (u32)__ballot(mvv != 0);
  const int g2 = t0 / 32 + w;                  // this wave's u32 word index
  if (lane == 0) {
    sV[w] = V32;
    vbit[b * W32_PER_B + g2] = V32;            // always (ws poisoned)
    if (V32) {
      atomicAdd(&len[b], __popc(V32));
      atomicMax(&mw[b], g2);
    }
  }
  __syncthreads();

  u32* plbase = pl + (size_t)b * KK * W32_PER_B + g2;  // + k*256 per k

  if ((sV[0] | sV[1] | sV[2] | sV[3]) == 0u) {
    // fully-invalid tile: zero-store our 4 plane words (ws poisoned), done
    plbase[(size_t)lane * W32_PER_B] = 0u;
    return;
  }

  // ---- stage 128 rows x 512 B via global->LDS DMA (no VGPR round-trip) ----
  {
    const char* gsrc = (const char*)(gt + (size_t)(b * TV + t0) * TS);
    char* lbase = (char*)gtile;
#pragma unroll
    for (int i = 0; i < 16; ++i) {
      const int off = (w * 16 + i) * 1024;     // wave-uniform 1KB chunk
      __builtin_amdgcn_global_load_lds(
          (const __attribute__((address_space(1))) u32*)(gsrc + off +
                                                         lane * 16),
          (__attribute__((address_space(3))) u32*)(lbase + off), 16, 0, 0);
    }
  }
  __syncthreads();                             // drains vmcnt (m97 behavior)

  // ---- transpose read: lane = k reads column idx[k], rows [32w, 32w+32) ----
  const int c = idx[lane];
  const int* col = gtile + 32 * w * TS + c;
  u32 plane = 0;
#pragma unroll
  for (int r = 0; r < 32; ++r)
    if (col[r * TS] > 0) plane |= 1u << r;
  plane &= sV[w];                              // aligned requires valid

  plbase[(size_t)lane * W32_PER_B] = plane;
}

// ---------------------------------------------------------------------------
// K3: one block per (k,b) row of pi. Direct stores, no global atomics.
// (byte-identical to R9 — measured fast)
// ---------------------------------------------------------------------------
__global__ __launch_bounds__(256, 4) void reduce_kernel(
    const float* __restrict__ po, const float* __restrict__ pi,
    const u32* __restrict__ vbit, const u32* __restrict__ pl,
    const int* __restrict__ mw,
    float* __restrict__ gsa, float* __restrict__ gsv,
    float* __restrict__ gca) {
  const int tid = threadIdx.x;
  const int lane = tid & 63;
  const int w = tid >> 6;
  const int kb = blockIdx.x;                   // k*BB + b
  const int b = kb & (BB - 1);
  const int k = kb >> 5;
  const u64* plrow = (const u64*)pl + (size_t)(b * KK + k) * W64_PER_B;
  const u64* vrow = (const u64*)vbit + (size_t)b * W64_PER_B;
  const float* pirow = pi + (size_t)kb * TV;
  const float* porow = po + (size_t)b * TV;

  __shared__ float rs[4][2];
  __shared__ int rca;
  if (tid == 0) rca = 0;
  __syncthreads();

  // chunks of 1024 floats; clip by highest valid word (mw in u32-word units)
  const int nch = min(8, (mw[b] + 32) >> 5);
  const int sh = (tid & 15) * 4;               // nibble of this thread's 4 t's
  float sa = 0.f, sv = 0.f;
#pragma unroll 2
  for (int c = 0; c < nch; ++c) {
    const int t = c * 1024 + tid * 4;
    const int widx = t >> 6;                   // u64 word
    const u64 vw = vrow[widx];                 // 16 lanes share -> L1 broadcast
    const u32 vb4 = (u32)((vw >> sh) & 15ull);
    if (vb4) {                                 // aligned subset of valid
      const u64 aw = plrow[widx];
      const u32 ab4 = (u32)((aw >> sh) & 15ull);
      const float4 x = *(const float4*)(pirow + t);
      const float4 p = *(const float4*)(porow + t);   // po: L2-resident (1MB)
      const float e0 =
          fabsf(__fdividef(1.f, 1.f + __expf(-p.x)) -
                __fdividef(1.f, 1.f + __expf(-x.x)));
      const float e1 =
          fabsf(__fdividef(1.f, 1.f + __expf(-p.y)) -
                __fdividef(1.f, 1.f + __expf(-x.y)));
      const float e2 =
          fabsf(__fdividef(1.f, 1.f + __expf(-p.z)) -
                __fdividef(1.f, 1.f + __expf(-x.z)));
      const float e3 =
          fabsf(__fdividef(1.f, 1.f + __expf(-p.w)) -
                __fdividef(1.f, 1.f + __expf(-x.w)));
      if (vb4 & 1u) sv += e0;
      if (vb4 & 2u) sv += e1;
      if (vb4 & 4u) sv += e2;
      if (vb4 & 8u) sv += e3;
      if (ab4 & 1u) sa += e0;
      if (ab4 & 2u) sa += e1;
      if (ab4 & 4u) sa += e2;
      if (ab4 & 8u) sa += e3;
    }
  }
  // 64-lane butterfly, then 4-wave combine
#pragma unroll
  for (int off = 32; off; off >>= 1) {
    sa += __shfl_xor(sa, off);
    sv += __shfl_xor(sv, off);
  }
  if (lane == 0) {
    rs[w][0] = sa;
    rs[w][1] = sv;
  }
  if (tid < W64_PER_B) atomicAdd(&rca, __popcll(plrow[tid]));  // LDS atomic
  __syncthreads();
  if (tid == 0) {
    gsa[kb] = rs[0][0] + rs[1][0] + rs[2][0] + rs[3][0];
    gsv[kb] = rs[0][1] + rs[1][1] + rs[2][1] + rs[3][1];
    gca[kb] = (float)rca;
  }
}

// ---------------------------------------------------------------------------
// Finalize: 1 block over the 2048 (k,b) pairs (logic verified in R2/R3).
// ---------------------------------------------------------------------------
__global__ __launch_bounds__(256) void fin_kernel(
    const float* __restrict__ gsa, const float* __restrict__ gsv,
    const float* __restrict__ gca, const int* __restrict__ len,
    float* __restrict__ out) {
  float s = 0.f;
  for (int i = threadIdx.x; i < KB_PAIRS; i += 256) {
    const int b = i & (BB - 1);
    const float ca = gca[i];
    const float cn = (float)len[b] - ca;
    if (ca > 0.f && cn > 0.f) {
      const float sa = gsa[i];
      const float sv = gsv[i];
      const float d = MARGIN_F - (sa / ca - (sv - sa) / cn);
      s += d > 0.f ? d : 0.f;
    }
  }
#pragma unroll
  for (int off = 32; off > 0; off >>= 1) s += __shfl_down(s, off);
  __shared__ float ws4[4];
  if ((threadIdx.x & 63) == 0) ws4[threadIdx.x >> 6] = s;
  __syncthreads();
  if (threadIdx.x == 0) {
    const float S = ws4[0] + ws4[1] + ws4[2] + ws4[3];
    const float ac = S * (1.0f / (float)KB_PAIRS);
    out[0] = ac;
    out[1] = ac * LAMBDA_F;
  }
}

extern "C" void kernel_launch(void* const* d_in, const int* in_sizes, int n_in,
                              void* d_out, int out_size, void* d_ws, size_t ws_size,
                              hipStream_t stream) {
  const float* pred_orig = (const float*)d_in[0];   // [B,TV] fp32
  const float* pred_int  = (const float*)d_in[1];   // [K,B,TV] fp32
  const int*   idx       = (const int*)d_in[2];     // [K] int32
  const int*   gt        = (const int*)d_in[3];     // [B,TV,TS] int32
  const int*   mv        = (const int*)d_in[4];     // [B,TV] int32
  float* out = (float*)d_out;

  float* gsa = (float*)d_ws;                        // [2048]
  float* gsv = gsa + KB_PAIRS;                      // [2048]
  float* gca = gsv + KB_PAIRS;                      // [2048]
  int*   len = (int*)(gca + KB_PAIRS);              // [32]
  int*   mw  = len + BB;                            // [32]
  u32*   vbit = (u32*)(mw + BB);                    // [32*256]  32 KB
  u32*   pl   = vbit + BB * W32_PER_B;              // [32*64*256] 2 MB

  // only len+mw need zeroing (256 B); everything else is written before read
  hipMemsetAsync(len, 0, 2 * BB * sizeof(int), stream);
  plane_kernel<<<BB * (TV / ROWS), 256, 0, stream>>>(idx, gt, mv, vbit, pl,
                                                     len, mw);
  reduce_kernel<<<KB_PAIRS, 256, 0, stream>>>(pred_orig, pred_int, vbit, pl,
                                              mw, gsa, gsv, gca);
  fin_kernel<<<1, 256, 0, stream>>>(gsa, gsv, gca, len, out);
}